// Round 4
// baseline (900.892 us; speedup 1.0000x reference)
//
#include <hip/hip_runtime.h>
#include <hip/hip_bf16.h>

// Net_79018808312147 — fused persistent kernel, R4.
// R3 evidence: 274 us invariant to HBM vs L3 source -> in-flight-limited.
// Fix: 32 waves/CU (512 blocks x 1024 thr, launch_bounds(1024,8) -> 2 blk/CU,
// VGPR<=64) + split-K=2 (half-row per wave, 2-deep double-buffered prefetch).
// In-flight ~= 32 waves x 2-4 KB = 64-128 KB/CU, covering multi-1000-cy
// loaded-chip latency. Cross-half combine via LDS partials.

#define DD 4096
#define NB 512      // 2 blocks per CU
#define NT 1024     // 16 waves; wave w: row_local = w>>1, half = w&1
#define NLAYER 4
#define ROWS_PER_BLOCK 8

__device__ __forceinline__ void grid_barrier(int* cnt) {
    __syncthreads();
    if (threadIdx.x == 0) {
        __threadfence();   // release
        __hip_atomic_fetch_add(cnt, 1, __ATOMIC_ACQ_REL, __HIP_MEMORY_SCOPE_AGENT);
        while (__hip_atomic_load(cnt, __ATOMIC_ACQUIRE, __HIP_MEMORY_SCOPE_AGENT) < NB)
            __builtin_amdgcn_s_sleep(2);
        __threadfence();   // acquire
    }
    __syncthreads();
}

// Dot of one half-row (2048 floats) against LDS vector, with W*O mask.
template<bool MASKED>
__device__ __forceinline__ float half_row_dot(const float* __restrict__ Wr,
                                              const float* __restrict__ Or,
                                              const float* __restrict__ sh,
                                              int half, int lane)
{
    const int base = half * 2048 + lane * 4;
    float4 w0 = *reinterpret_cast<const float4*>(Wr + base);
    float4 o0;
    if (MASKED) o0 = *reinterpret_cast<const float4*>(Or + base);

    float a0 = 0.f, a1 = 0.f, a2 = 0.f, a3 = 0.f;
    #pragma unroll
    for (int it = 0; it < 8; ++it) {
        float4 wn, on;
        if (it < 7) {
            wn = *reinterpret_cast<const float4*>(Wr + base + (it + 1) * 256);
            if (MASKED) on = *reinterpret_cast<const float4*>(Or + base + (it + 1) * 256);
        }
        float4 v = *reinterpret_cast<const float4*>(sh + base + it * 256);
        if (MASKED) { w0.x *= o0.x; w0.y *= o0.y; w0.z *= o0.z; w0.w *= o0.w; }
        a0 = fmaf(w0.x, v.x, a0);
        a1 = fmaf(w0.y, v.y, a1);
        a2 = fmaf(w0.z, v.z, a2);
        a3 = fmaf(w0.w, v.w, a3);
        w0 = wn;
        if (MASKED) o0 = on;
    }
    float acc = (a0 + a1) + (a2 + a3);
    #pragma unroll
    for (int off = 32; off; off >>= 1) acc += __shfl_xor(acc, off, 64);
    return acc;   // valid in lane 0
}

__global__ __launch_bounds__(NT, 8)   // 8 waves/EU min -> 2 blocks/CU, VGPR<=64
void fused_net(const float* __restrict__ x,
               const float* __restrict__ W_in,
               const float* __restrict__ b_in,
               const float* __restrict__ weights,
               const float* __restrict__ orders,
               const float* __restrict__ biases,
               const int*   __restrict__ gidx,
               const int*   __restrict__ sidx,
               float*       __restrict__ out,
               float*       __restrict__ buf0,
               float*       __restrict__ buf1,
               int*         __restrict__ cnt)
{
    __shared__ float sh[DD];
    __shared__ float partial[16];
    const int tid  = threadIdx.x;
    const int lane = tid & 63;
    const int wv   = tid >> 6;                       // 0..15
    const int rl   = wv >> 1;                        // row_local 0..7
    const int half = wv & 1;
    const int row  = blockIdx.x * ROWS_PER_BLOCK + rl;

    // ---------------- input layer: relu(W_in@x + b_in), scatter sidx[0] -----
    for (int j = tid; j < DD; j += NT) sh[j] = x[j];
    __syncthreads();
    {
        const float* Wr = W_in + (size_t)row * DD;
        float acc = half_row_dot<false>(Wr, nullptr, sh, half, lane);
        if (lane == 0) partial[wv] = acc;
    }
    __syncthreads();
    if (tid < ROWS_PER_BLOCK) {
        const int r = blockIdx.x * ROWS_PER_BLOCK + tid;
        float v = partial[2 * tid] + partial[2 * tid + 1] + b_in[r];
        buf0[sidx[r]] = fmaxf(v, 0.f);
    }
    grid_barrier(cnt + 0);

    // ---------------- masked layers ----------------------------------------
    float* bufs[2] = { buf0, buf1 };
    #pragma unroll
    for (int l = 0; l < NLAYER; ++l) {
        const float* src = bufs[l & 1];
        const int*   g   = gidx + (size_t)l * DD;
        for (int j = tid; j < DD; j += NT) sh[j] = src[g[j]];
        __syncthreads();

        const float* Wr = weights + (size_t)l * DD * DD + (size_t)row * DD;
        const float* Or = orders  + (size_t)l * DD * DD + (size_t)row * DD;
        float acc = half_row_dot<true>(Wr, Or, sh, half, lane);
        if (lane == 0) partial[wv] = acc;
        __syncthreads();

        if (tid < ROWS_PER_BLOCK) {
            const int r = blockIdx.x * ROWS_PER_BLOCK + tid;
            float v = partial[2 * tid] + partial[2 * tid + 1]
                    + biases[(size_t)l * DD + r];
            v = fmaxf(v, 0.f);
            if (l == NLAYER - 1) out[r] = v;                        // pre-scatter
            else bufs[(l + 1) & 1][sidx[(size_t)(l + 1) * DD + r]] = v;
        }
        if (l < NLAYER - 1) grid_barrier(cnt + 1 + l);
        else __syncthreads();   // keep sh free for reuse safety (no-op cost)
    }
}

extern "C" void kernel_launch(void* const* d_in, const int* in_sizes, int n_in,
                              void* d_out, int out_size, void* d_ws, size_t ws_size,
                              hipStream_t stream) {
    const float* x       = (const float*)d_in[0];
    const float* W_in    = (const float*)d_in[1];
    const float* b_in    = (const float*)d_in[2];
    const float* weights = (const float*)d_in[3];
    const float* orders  = (const float*)d_in[4];
    const float* biases  = (const float*)d_in[5];
    const int*   gidx    = (const int*)d_in[6];
    const int*   sidx    = (const int*)d_in[7];
    float*       out     = (float*)d_out;

    int*   cnt  = (int*)d_ws;                         // barrier counters
    float* buf0 = (float*)((char*)d_ws + 256);
    float* buf1 = buf0 + DD;

    hipMemsetAsync(d_ws, 0, 256, stream);             // zero counters (graph-safe)

    fused_net<<<NB, NT, 0, stream>>>(x, W_in, b_in, weights, orders, biases,
                                     gidx, sidx, out, buf0, buf1, cnt);
}

// Round 7
// 548.475 us; speedup vs baseline: 1.6425x; 1.6425x over previous
//
#include <hip/hip_runtime.h>
#include <hip/hip_bf16.h>

// Net_79018808312147 — R7 = R5 resubmit (R5: container failed, R6: GPU
// acquisition timeout — kernel never ran either time). 5-launch structure
// (R1, ~180 us GPU time, beat fused R3/R4), plus explicit 8-deep W+O register
// prefetch.
//
// Evidence so far: VALU ~2%, conflicts 0, vmem instr counts trivial, yet
// effective stream BW only 2-3.4 TB/s -> loaded-chip latency is multi-1000 cy;
// sustained BW ~ in-flight bytes/CU. R4 (VGPR=32, ~2 loads deep) halved BW.
// R5 forces depth: 16 waves/CU x 8 KB in flight (w[8]+o[8] float4 results =
// 64 VGPRs), prefetch issued BEFORE the LDS gather so gather latency and
// stream ramp overlap. launch_bounds(1024,4) -> VGPR cap 128, 1 block/CU.

#define DD 4096
#define BLOCK 1024   // 16 waves, one output row per wave
#define GRID  256    // 256 blocks = 1/CU; 16 rows/block

template<bool MASKED>
__global__ __launch_bounds__(BLOCK, 4)
void gemv_kernel(const float* __restrict__ W,
                 const float* __restrict__ O,
                 const float* __restrict__ bias,
                 const float* __restrict__ src,   // prev buffer (or x)
                 const int*   __restrict__ g,     // gather idx (null layer 0)
                 const int*   __restrict__ s,     // scatter idx (null final)
                 float*       __restrict__ dst)
{
    __shared__ float sh[DD];
    const int tid  = threadIdx.x;
    const int lane = tid & 63;
    const int wv   = tid >> 6;
    const int row  = blockIdx.x * 16 + wv;

    const float* __restrict__ Wr = W + (size_t)row * DD + lane * 4;
    const float* __restrict__ Or = MASKED ? (O + (size_t)row * DD + lane * 4)
                                          : nullptr;

    // ---- issue 8-deep W/O prefetch FIRST (16 independent 1KB wave-loads) ---
    float4 wb[8], ob[8];
    #pragma unroll
    for (int k = 0; k < 8; ++k) {
        wb[k] = *reinterpret_cast<const float4*>(Wr + k * 256);
        if (MASKED) ob[k] = *reinterpret_cast<const float4*>(Or + k * 256);
    }

    // ---- stage (gathered) input vector into LDS (latency hides under ramp) -
    #pragma unroll
    for (int j = tid; j < DD; j += BLOCK)
        sh[j] = MASKED ? src[g[j]] : src[j];
    __syncthreads();

    // ---- consume batch k while issuing batch k+8 ---------------------------
    float a0 = 0.f, a1 = 0.f, a2 = 0.f, a3 = 0.f;
    #pragma unroll
    for (int it = 0; it < 16; ++it) {
        float4 v = *reinterpret_cast<const float4*>(sh + it * 256 + lane * 4);
        float4 w = wb[it & 7];
        float4 o;
        if (MASKED) o = ob[it & 7];
        if (it < 8) {
            wb[it] = *reinterpret_cast<const float4*>(Wr + (it + 8) * 256);
            if (MASKED) ob[it] = *reinterpret_cast<const float4*>(Or + (it + 8) * 256);
        }
        if (MASKED) { w.x *= o.x; w.y *= o.y; w.z *= o.z; w.w *= o.w; }
        a0 = fmaf(w.x, v.x, a0);
        a1 = fmaf(w.y, v.y, a1);
        a2 = fmaf(w.z, v.z, a2);
        a3 = fmaf(w.w, v.w, a3);
    }
    float acc = (a0 + a1) + (a2 + a3);

    #pragma unroll
    for (int off = 32; off; off >>= 1) acc += __shfl_xor(acc, off, 64);

    if (lane == 0) {
        float r = fmaxf(acc + bias[row], 0.f);
        if (s) dst[s[row]] = r;   // scatter (permutation) into next buffer
        else   dst[row]    = r;   // final layer: pre-scatter output
    }
}

extern "C" void kernel_launch(void* const* d_in, const int* in_sizes, int n_in,
                              void* d_out, int out_size, void* d_ws, size_t ws_size,
                              hipStream_t stream) {
    const float* x       = (const float*)d_in[0];
    const float* W_in    = (const float*)d_in[1];
    const float* b_in    = (const float*)d_in[2];
    const float* weights = (const float*)d_in[3];
    const float* orders  = (const float*)d_in[4];
    const float* biases  = (const float*)d_in[5];
    const int*   gidx    = (const int*)d_in[6];
    const int*   sidx    = (const int*)d_in[7];
    float*       out     = (float*)d_out;

    float* buf0 = (float*)d_ws;
    float* buf1 = buf0 + DD;

    // Input layer: relu(W_in @ x + b_in), scattered by scatter_idx[0].
    gemv_kernel<false><<<GRID, BLOCK, 0, stream>>>(
        W_in, nullptr, b_in, x, nullptr, sidx, buf0);

    float* cur = buf0;
    float* nxt = buf1;
    for (int l = 0; l < 4; ++l) {
        const int* s  = (l == 3) ? nullptr : (sidx + (size_t)(l + 1) * DD);
        float*     d  = (l == 3) ? out     : nxt;
        gemv_kernel<true><<<GRID, BLOCK, 0, stream>>>(
            weights + (size_t)l * DD * DD,
            orders  + (size_t)l * DD * DD,
            biases  + (size_t)l * DD,
            cur, gidx + (size_t)l * DD, s, d);
        float* t = cur; cur = nxt; nxt = t;
    }
}